// Round 15
// baseline (788.755 us; speedup 1.0000x reference)
//
#include <hip/hip_runtime.h>

typedef unsigned short u16;
typedef __attribute__((ext_vector_type(8))) short short8;
typedef __attribute__((ext_vector_type(8))) unsigned short ushort8v;
typedef __attribute__((ext_vector_type(4))) float f32x4;

#define B_ 8
#define T_ 256
#define U_ 64
#define E_ 512
#define J_ 640
#define V_ 1024

__device__ __forceinline__ u16 f2bf(float f) {
  unsigned int u = __float_as_uint(f);
  u += 0x7fffu + ((u >> 16) & 1u);   // round-to-nearest-even
  return (u16)(u >> 16);
}

__device__ __forceinline__ void gload16(const void* g, void* l) {
  __builtin_amdgcn_global_load_lds((const __attribute__((address_space(1))) void*)g,
                                   (__attribute__((address_space(3))) void*)l,
                                   16, 0, 0);
}

// ---------------- fused cast fp32 -> bf16 for all 5 inputs (dsts contiguous in ws) --------
__global__ __launch_bounds__(256) void cast5_k(const float4* __restrict__ s0,
                                               const float4* __restrict__ s1,
                                               const float4* __restrict__ s2,
                                               const float4* __restrict__ s3,
                                               const float4* __restrict__ s4,
                                               ushort4* __restrict__ dst) {
  int i = blockIdx.x * 256 + threadIdx.x;
  const int st = gridDim.x * 256;
  for (; i < 655360; i += st) {
    const float4* s; int off;
    if (i < 262144)      { s = s0; off = 0; }
    else if (i < 327680) { s = s1; off = 262144; }
    else if (i < 409600) { s = s2; off = 327680; }
    else if (i < 491520) { s = s3; off = 409600; }
    else                 { s = s4; off = 491520; }
    float4 v = s[i - off];
    ushort4 o;
    o.x = f2bf(v.x); o.y = f2bf(v.y); o.z = f2bf(v.z); o.w = f2bf(v.w);
    dst[i] = o;
  }
}

// ---------------- projection GEMM (small, latency-tolerant) ----------------
__global__ __launch_bounds__(256) void proj_k(const u16* __restrict__ X,
                                              const u16* __restrict__ W,
                                              float* __restrict__ C) {
  __shared__ __align__(16) u16 As[128 * 32];
  __shared__ __align__(16) u16 Bs[128 * 32];
  const int tid = threadIdx.x;
  const int w = tid >> 6, lane = tid & 63;
  const int wr = w >> 1, wc = w & 1;
  const int m0 = blockIdx.x * 128, n0 = blockIdx.y * 128;
  const int lr = lane & 15, lk = lane >> 4;
  const int r4 = tid >> 2, kq = tid & 3;

  f32x4 acc[4][4] = {};

  for (int ks = 0; ks < E_ / 32; ++ks) {
    const int k0 = ks * 32;
    gload16(X + (size_t)(m0 + r4) * E_ + k0 + kq * 8, (char*)As + w * 1024);
    gload16(X + (size_t)(m0 + 64 + r4) * E_ + k0 + kq * 8, (char*)As + 4096 + w * 1024);
    gload16(W + (size_t)(n0 + r4) * E_ + k0 + kq * 8, (char*)Bs + w * 1024);
    gload16(W + (size_t)(n0 + 64 + r4) * E_ + k0 + kq * 8, (char*)Bs + 4096 + w * 1024);
    __syncthreads();
    short8 a[4], bb[4];
#pragma unroll
    for (int m = 0; m < 4; ++m)
      a[m] = *(const short8*)&As[(wr * 64 + m * 16 + lr) * 32 + lk * 8];
#pragma unroll
    for (int n = 0; n < 4; ++n)
      bb[n] = *(const short8*)&Bs[(wc * 64 + n * 16 + lr) * 32 + lk * 8];
#pragma unroll
    for (int m = 0; m < 4; ++m)
#pragma unroll
      for (int n = 0; n < 4; ++n)
        acc[m][n] = __builtin_amdgcn_mfma_f32_16x16x32_bf16(a[m], bb[n], acc[m][n], 0, 0, 0);
    __syncthreads();
  }

#pragma unroll
  for (int m = 0; m < 4; ++m) {
    const int row = m0 + wr * 64 + m * 16 + lk * 4;
#pragma unroll
    for (int n = 0; n < 4; ++n) {
      const int col = n0 + wc * 64 + n * 16 + lr;
#pragma unroll
      for (int i = 0; i < 4; ++i)
        C[(size_t)(row + i) * J_ + col] = acc[m][n][i];
    }
  }
}

// ---------------- Wo fragment pre-pack ----------------
// pk[((vt*20+ks)*4+nq)*512 + lane*8 + e] = Wo[vt*64+nq*16+(lane&15)][ks*32+(lane>>4)*8+e]
__global__ __launch_bounds__(256) void pack_k(const u16* __restrict__ Wo,
                                              u16* __restrict__ pk) {
  const int u = blockIdx.x * 256 + threadIdx.x;   // 81920 units of short8
  const int l = u & 63;
  int r = u >> 6;
  const int nq = r & 3;  r >>= 2;
  const int ks = r % 20;
  const int vt = r / 20;
  const int v = vt * 64 + nq * 16 + (l & 15);
  const int k = ks * 32 + (l >> 4) * 8;
  *(short8*)(pk + (size_t)u * 8) = *(const short8*)(Wo + (size_t)v * J_ + k);
}

// ---------------- fused joint v5: 512 thr, 40 KiB half-K A-panel -> 2 blocks/CU ----------
// Block = one (b,t) = 64 rows. A-panel holds HALF the K range: [64][320] bf16 = 40 KiB.
// 4 compute phases (c2=0:H0, c2=0:H1, c2=1:H1, c2=1:H0), 3 silu builds (H1 reused).
// VGPR <= 128 (launch_bounds(512,4)) + 40 KiB -> 2 blocks/CU: one block's builds/
// epilogue/ramp overlap the other's K-loop. B-prefetch chains across phase barriers.
__global__ __launch_bounds__(512, 4) void fused5_k(const float* __restrict__ ep,
                                                   const float* __restrict__ pp,
                                                   const u16* __restrict__ pk,
                                                   float* __restrict__ out) {
  __shared__ __align__(16) u16 Alds[64 * 320];   // 40 KiB
  const int tid = threadIdx.x;
  const int w = tid >> 6, lane = tid & 63;
  const int lr = lane & 15, lk = lane >> 4;
  const int bt = blockIdx.x;                 // b*256 + t
  const int b = bt >> 8;
  const size_t m0 = (size_t)bt * 64;
  const int rx = lr & 7;

  const u16* bp0 = pk + (size_t)(2 * w) * 40960 + lane * 8;   // vt = 2w
  const u16* bp1 = bp0 + 40960;                               // vt = 2w+1

  const float* eprow = ep + (size_t)bt * J_;
  const float* pbase = pp + (size_t)b * 64 * J_;

  short8 BE[4], BO[4], a[4];

#define BL(bF, bp, ks)                                                         \
  do {                                                                         \
    _Pragma("unroll")                                                          \
    for (int nq = 0; nq < 4; ++nq)                                             \
      bF[nq] = *(const short8*)((bp) + (ks) * 2048 + nq * 512);                \
  } while (0)

  // silu build of half h (k columns h*320 .. h*320+319), swizzled
#define BUILD(h)                                                               \
  do {                                                                         \
    _Pragma("unroll")                                                          \
    for (int it = 0; it < 5; ++it) {                                           \
      const int unit = tid + it * 512;       /* 2560 units = 64 rows x 40 ch */\
      const int row = unit / 40;                                               \
      const int c = unit - row * 40;                                           \
      const int kg = (h) * 320 + c * 8;                                        \
      union { float4 v[2]; float f[8]; } Ee, Pp;                               \
      Ee.v[0] = *(const float4*)(eprow + kg);                                  \
      Ee.v[1] = *(const float4*)(eprow + kg + 4);                              \
      Pp.v[0] = *(const float4*)(pbase + (size_t)row * J_ + kg);               \
      Pp.v[1] = *(const float4*)(pbase + (size_t)row * J_ + kg + 4);           \
      union { ushort8v v; u16 s[8]; } R;                                       \
      _Pragma("unroll")                                                        \
      for (int j = 0; j < 8; ++j) {                                            \
        float x = Ee.f[j] + Pp.f[j];                                           \
        R.s[j] = f2bf(x * __builtin_amdgcn_rcpf(1.0f + __expf(-x)));           \
      }                                                                        \
      *(ushort8v*)&Alds[row * 320 + ((c ^ (row & 7)) << 3)] = R.v;             \
    }                                                                          \
  } while (0)

#define AR(ksl)                                                                \
  do {                                                                         \
    _Pragma("unroll")                                                          \
    for (int mq = 0; mq < 4; ++mq)                                             \
      a[mq] = *(const short8*)&Alds[(mq * 16 + lr) * 320 +                     \
                                    ((((ksl) * 4 + lk) ^ rx) << 3)];           \
  } while (0)

#define MM(bF, acc)                                                            \
  do {                                                                         \
    _Pragma("unroll")                                                          \
    for (int mq = 0; mq < 4; ++mq)                                             \
      _Pragma("unroll")                                                        \
      for (int nq = 0; nq < 4; ++nq)                                           \
        acc[mq][nq] = __builtin_amdgcn_mfma_f32_16x16x32_bf16(bF[nq], a[mq],   \
                                                              acc[mq][nq], 0, 0, 0); \
  } while (0)

  // 10 K-steps on the current panel half; BE preloaded with (bp,ks0); final
  // prefetch loads (bpn,ksn) for the NEXT phase into BE.
#define KLOOP10(bp, ks0, acc, bpn, ksn)                                        \
  do {                                                                         \
    _Pragma("unroll")                                                          \
    for (int it = 0; it < 5; ++it) {                                           \
      BL(BO, bp, (ks0) + 2 * it + 1);                                          \
      AR(2 * it);                                                              \
      MM(BE, acc);                                                             \
      if (it < 4) BL(BE, bp, (ks0) + 2 * it + 2);                              \
      else        BL(BE, bpn, ksn);                                            \
      AR(2 * it + 1);                                                          \
      MM(BO, acc);                                                             \
    }                                                                          \
  } while (0)

#define STORE(acc, vtc)                                                        \
  do {                                                                         \
    _Pragma("unroll")                                                          \
    for (int mq = 0; mq < 4; ++mq) {                                           \
      const size_t row = m0 + mq * 16 + lr;                                    \
      _Pragma("unroll")                                                        \
      for (int nq = 0; nq < 4; ++nq) {                                         \
        const int col = (vtc) * 64 + nq * 16 + lk * 4;                         \
        *(float4*)&out[row * V_ + col] = *(float4*)&acc[mq][nq];               \
      }                                                                        \
    }                                                                          \
  } while (0)

  BL(BE, bp0, 0);                       // prefetch: hides under first build
  BUILD(0);
  __syncthreads();

  {
    f32x4 acc0[4][4] = {};
    KLOOP10(bp0, 0, acc0, bp0, 10);     // phase A: c2=0, ks 0-9 on H0
    __syncthreads();                    // all H0 reads retired
    BUILD(1);
    __syncthreads();
    KLOOP10(bp0, 10, acc0, bp1, 10);    // phase B: c2=0, ks 10-19 on H1
    STORE(acc0, 2 * w);
  }
  {
    f32x4 acc1[4][4] = {};
    KLOOP10(bp1, 10, acc1, bp1, 0);     // phase C: c2=1, ks 10-19 on H1 (reuse)
    __syncthreads();                    // all H1 reads retired
    BUILD(0);
    __syncthreads();
    KLOOP10(bp1, 0, acc1, bp1, 0);      // phase D: c2=1, ks 0-9 on H0 (dup tail prefetch, harmless)
    STORE(acc1, 2 * w + 1);
  }
#undef BL
#undef BUILD
#undef AR
#undef MM
#undef KLOOP10
#undef STORE
}

extern "C" void kernel_launch(void* const* d_in, const int* in_sizes, int n_in,
                              void* d_out, int out_size, void* d_ws, size_t ws_size,
                              hipStream_t stream) {
  const float* enc = (const float*)d_in[0];   // [8,256,512]
  const float* pred = (const float*)d_in[1];  // [8,64,512]
  const float* We = (const float*)d_in[2];    // [640,512]
  const float* Wp = (const float*)d_in[3];    // [640,512]
  const float* Wo = (const float*)d_in[4];    // [1024,640]
  float* out = (float*)d_out;                 // [8,256,64,1024]

  char* ws = (char*)d_ws;
  u16* enc_bf = (u16*)ws;                     // 2,097,152 B
  u16* pred_bf = (u16*)(ws + 2097152);        //   524,288 B
  u16* We_bf = (u16*)(ws + 2621440);          //   655,360 B
  u16* Wp_bf = (u16*)(ws + 3276800);          //   655,360 B
  u16* Wo_bf = (u16*)(ws + 3932160);          // 1,310,720 B -> ends 5,242,880
  float* ep = (float*)(ws + 5242880);         // 5,242,880 B  [2048][640]
  float* pp = (float*)(ws + 10485760);        // 1,310,720 B  [512][640] -> ends 11,796,480
  u16* Wo_pk = (u16*)(ws + 11796480);         // 1,310,720 B packed fragments -> ends 13,107,200

  cast5_k<<<2048, 256, 0, stream>>>((const float4*)enc, (const float4*)pred,
                                    (const float4*)We, (const float4*)Wp,
                                    (const float4*)Wo, (ushort4*)ws);

  proj_k<<<dim3(16, 5), 256, 0, stream>>>(enc_bf, We_bf, ep);  // [2048][640]
  proj_k<<<dim3(4, 5), 256, 0, stream>>>(pred_bf, Wp_bf, pp);  // [512][640]
  pack_k<<<320, 256, 0, stream>>>(Wo_bf, Wo_pk);

  fused5_k<<<2048, 512, 0, stream>>>(ep, pp, Wo_pk, out);
}

// Round 16
// 242.021 us; speedup vs baseline: 3.2590x; 3.2590x over previous
//
#include <hip/hip_runtime.h>

typedef unsigned short u16;
typedef __attribute__((ext_vector_type(8))) short short8;
typedef __attribute__((ext_vector_type(8))) unsigned short ushort8v;
typedef __attribute__((ext_vector_type(4))) float f32x4;

#define B_ 8
#define T_ 256
#define U_ 64
#define E_ 512
#define J_ 640
#define V_ 1024
#define NT 20

__device__ __forceinline__ u16 f2bf(float f) {
  unsigned int u = __float_as_uint(f);
  u += 0x7fffu + ((u >> 16) & 1u);   // round-to-nearest-even
  return (u16)(u >> 16);
}

__device__ __forceinline__ void gload16(const void* g, void* l) {
  __builtin_amdgcn_global_load_lds((const __attribute__((address_space(1))) void*)g,
                                   (__attribute__((address_space(3))) void*)l,
                                   16, 0, 0);
}

// ---------------- fused cast fp32 -> bf16 for all 5 inputs (dsts contiguous in ws) --------
__global__ __launch_bounds__(256) void cast5_k(const float4* __restrict__ s0,
                                               const float4* __restrict__ s1,
                                               const float4* __restrict__ s2,
                                               const float4* __restrict__ s3,
                                               const float4* __restrict__ s4,
                                               ushort4* __restrict__ dst) {
  int i = blockIdx.x * 256 + threadIdx.x;
  const int st = gridDim.x * 256;
  for (; i < 655360; i += st) {
    const float4* s; int off;
    if (i < 262144)      { s = s0; off = 0; }
    else if (i < 327680) { s = s1; off = 262144; }
    else if (i < 409600) { s = s2; off = 327680; }
    else if (i < 491520) { s = s3; off = 409600; }
    else                 { s = s4; off = 491520; }
    float4 v = s[i - off];
    ushort4 o;
    o.x = f2bf(v.x); o.y = f2bf(v.y); o.z = f2bf(v.z); o.w = f2bf(v.w);
    dst[i] = o;
  }
}

// ---------------- projection GEMM (small, latency-tolerant) ----------------
__global__ __launch_bounds__(256) void proj_k(const u16* __restrict__ X,
                                              const u16* __restrict__ W,
                                              float* __restrict__ C) {
  __shared__ __align__(16) u16 As[128 * 32];
  __shared__ __align__(16) u16 Bs[128 * 32];
  const int tid = threadIdx.x;
  const int w = tid >> 6, lane = tid & 63;
  const int wr = w >> 1, wc = w & 1;
  const int m0 = blockIdx.x * 128, n0 = blockIdx.y * 128;
  const int lr = lane & 15, lk = lane >> 4;
  const int r4 = tid >> 2, kq = tid & 3;

  f32x4 acc[4][4] = {};

  for (int ks = 0; ks < E_ / 32; ++ks) {
    const int k0 = ks * 32;
    gload16(X + (size_t)(m0 + r4) * E_ + k0 + kq * 8, (char*)As + w * 1024);
    gload16(X + (size_t)(m0 + 64 + r4) * E_ + k0 + kq * 8, (char*)As + 4096 + w * 1024);
    gload16(W + (size_t)(n0 + r4) * E_ + k0 + kq * 8, (char*)Bs + w * 1024);
    gload16(W + (size_t)(n0 + 64 + r4) * E_ + k0 + kq * 8, (char*)Bs + 4096 + w * 1024);
    __syncthreads();
    short8 a[4], bb[4];
#pragma unroll
    for (int m = 0; m < 4; ++m)
      a[m] = *(const short8*)&As[(wr * 64 + m * 16 + lr) * 32 + lk * 8];
#pragma unroll
    for (int n = 0; n < 4; ++n)
      bb[n] = *(const short8*)&Bs[(wc * 64 + n * 16 + lr) * 32 + lk * 8];
#pragma unroll
    for (int m = 0; m < 4; ++m)
#pragma unroll
      for (int n = 0; n < 4; ++n)
        acc[m][n] = __builtin_amdgcn_mfma_f32_16x16x32_bf16(a[m], bb[n], acc[m][n], 0, 0, 0);
    __syncthreads();
  }

#pragma unroll
  for (int m = 0; m < 4; ++m) {
    const int row = m0 + wr * 64 + m * 16 + lk * 4;
#pragma unroll
    for (int n = 0; n < 4; ++n) {
      const int col = n0 + wc * 64 + n * 16 + lr;
#pragma unroll
      for (int i = 0; i < 4; ++i)
        C[(size_t)(row + i) * J_ + col] = acc[m][n][i];
    }
  }
}

// ---------------- Wo fragment pre-pack ----------------
// pk[((vt*20+ks)*4+nq)*512 + lane*8 + e] = Wo[vt*64+nq*16+(lane&15)][ks*32+(lane>>4)*8+e]
__global__ __launch_bounds__(256) void pack_k(const u16* __restrict__ Wo,
                                              u16* __restrict__ pk) {
  const int u = blockIdx.x * 256 + threadIdx.x;   // 81920 units of short8
  const int l = u & 63;
  int r = u >> 6;
  const int nq = r & 3;  r >>= 2;
  const int ks = r % 20;
  const int vt = r / 20;
  const int v = vt * 64 + nq * 16 + (l & 15);
  const int k = ks * 32 + (l >> 4) * 8;
  *(short8*)(pk + (size_t)u * 8) = *(const short8*)(Wo + (size_t)v * J_ + k);
}

// ---------------- fused joint v6: bt-PAIRED, B-frags shared across two A-panels ----------
// Block = two (b,t) values (bt0=2*bid, bt1=bt0+1): two 64x640 A-panels in LDS (160 KiB).
// 8 waves; wave does 2 passes (vt = w, w+8). Per pass: barrier-free K-loop, each B-frag
// set (coalesced 1KB loads from L2 pack) is MFMA'd against BOTH panels -> B-L2 traffic
// halved vs r11. mfma(b,a) swapped operands -> dwordx4 epilogue. VGPR ~210 (no cap).
__global__ __launch_bounds__(512, 2) void fused6_k(const float* __restrict__ ep,
                                                   const float* __restrict__ pp,
                                                   const u16* __restrict__ pk,
                                                   float* __restrict__ out) {
  __shared__ __align__(16) u16 Alds[2][64 * 640];   // 160 KiB (full CU pool)
  const int tid = threadIdx.x;
  const int w = tid >> 6, lane = tid & 63;
  const int lr = lane & 15, lk = lane >> 4;
  const int bt0 = blockIdx.x * 2;
  const int b = bt0 >> 8;
  const size_t m00 = (size_t)bt0 * 64;          // bt0 rows; bt1 rows = +64
  const int rx = lr & 7;

  const u16* bpA = pk + (size_t)w * 40960 + lane * 8;        // pass 0: vt = w
  const u16* bpB = pk + (size_t)(w + 8) * 40960 + lane * 8;  // pass 1: vt = w+8

  const float* ep0 = ep + (size_t)bt0 * J_;
  const float* pbase = pp + (size_t)b * 64 * J_;

  short8 BE[4], BO[4], a0[4], a1[4];

#define BL(bF, bp, ks)                                                         \
  do {                                                                         \
    _Pragma("unroll")                                                          \
    for (int nq = 0; nq < 4; ++nq)                                             \
      bF[nq] = *(const short8*)((bp) + (ks) * 2048 + nq * 512);                \
  } while (0)

  BL(BE, bpA, 0);   // prefetch: hides under panel builds

  // ---- phase 1: build BOTH swizzled A-panels (20 units/thread, 10240 units) ----
#pragma unroll
  for (int it = 0; it < 20; ++it) {
    const int unit = tid + it * 512;
    const int pnl = unit >= 5120;
    const int u2 = unit - pnl * 5120;
    const int row = u2 / 80;
    const int c = u2 - row * 80;
    const float* er = ep0 + pnl * J_ + c * 8;
    const float* pr = pbase + (size_t)row * J_ + c * 8;
    union { float4 v[2]; float f[8]; } Ee, Pp;
    Ee.v[0] = *(const float4*)er;       Ee.v[1] = *(const float4*)(er + 4);
    Pp.v[0] = *(const float4*)pr;       Pp.v[1] = *(const float4*)(pr + 4);
    union { ushort8v v; u16 s[8]; } R;
#pragma unroll
    for (int j = 0; j < 8; ++j) {
      float x = Ee.f[j] + Pp.f[j];
      R.s[j] = f2bf(x * __builtin_amdgcn_rcpf(1.0f + __expf(-x)));
    }
    *(ushort8v*)&Alds[pnl][row * 640 + ((c ^ (row & 7)) << 3)] = R.v;
  }
  __syncthreads();                            // the ONLY barrier

  // ---- phase 2: two passes, barrier-free K-loops; B shared across both panels ----
#define AR2(ks)                                                                \
  do {                                                                         \
    _Pragma("unroll")                                                          \
    for (int mq = 0; mq < 4; ++mq) {                                           \
      const int off = (mq * 16 + lr) * 640 + ((((ks) * 4 + lk) ^ rx) << 3);    \
      a0[mq] = *(const short8*)&Alds[0][off];                                  \
      a1[mq] = *(const short8*)&Alds[1][off];                                  \
    }                                                                          \
  } while (0)

#define MM2(bF)                                                                \
  do {                                                                         \
    __builtin_amdgcn_s_setprio(1);                                             \
    _Pragma("unroll")                                                          \
    for (int mq = 0; mq < 4; ++mq)                                             \
      _Pragma("unroll")                                                        \
      for (int nq = 0; nq < 4; ++nq) {                                         \
        acc0[mq][nq] = __builtin_amdgcn_mfma_f32_16x16x32_bf16(bF[nq], a0[mq], \
                                                               acc0[mq][nq], 0, 0, 0); \
        acc1[mq][nq] = __builtin_amdgcn_mfma_f32_16x16x32_bf16(bF[nq], a1[mq], \
                                                               acc1[mq][nq], 0, 0, 0); \
      }                                                                        \
    __builtin_amdgcn_s_setprio(0);                                             \
  } while (0)

#define STORE2(vtc)                                                            \
  do {                                                                         \
    _Pragma("unroll")                                                          \
    for (int mq = 0; mq < 4; ++mq) {                                           \
      const size_t r0 = m00 + mq * 16 + lr;                                    \
      _Pragma("unroll")                                                        \
      for (int nq = 0; nq < 4; ++nq) {                                         \
        const int col = (vtc) * 64 + nq * 16 + lk * 4;                         \
        *(float4*)&out[r0 * V_ + col] = *(float4*)&acc0[mq][nq];               \
        *(float4*)&out[(r0 + 64) * V_ + col] = *(float4*)&acc1[mq][nq];        \
      }                                                                        \
    }                                                                          \
  } while (0)

  {
    f32x4 acc0[4][4] = {}, acc1[4][4] = {};
#pragma unroll 1
    for (int it = 0; it < NT / 2; ++it) {
      BL(BO, bpA, 2 * it + 1);
      AR2(2 * it);
      MM2(BE);
      __builtin_amdgcn_sched_barrier(0);
      if (it < NT / 2 - 1) BL(BE, bpA, 2 * it + 2);
      else                 BL(BE, bpB, 0);          // chain into pass 1
      AR2(2 * it + 1);
      MM2(BO);
      __builtin_amdgcn_sched_barrier(0);
    }
    STORE2(w);
  }
  {
    f32x4 acc0[4][4] = {}, acc1[4][4] = {};
#pragma unroll 1
    for (int it = 0; it < NT / 2; ++it) {
      BL(BO, bpB, 2 * it + 1);
      AR2(2 * it);
      MM2(BE);
      __builtin_amdgcn_sched_barrier(0);
      if (it < NT / 2 - 1) BL(BE, bpB, 2 * it + 2);
      AR2(2 * it + 1);
      MM2(BO);
      __builtin_amdgcn_sched_barrier(0);
    }
    STORE2(w + 8);
  }
#undef BL
#undef AR2
#undef MM2
#undef STORE2
}

extern "C" void kernel_launch(void* const* d_in, const int* in_sizes, int n_in,
                              void* d_out, int out_size, void* d_ws, size_t ws_size,
                              hipStream_t stream) {
  const float* enc = (const float*)d_in[0];   // [8,256,512]
  const float* pred = (const float*)d_in[1];  // [8,64,512]
  const float* We = (const float*)d_in[2];    // [640,512]
  const float* Wp = (const float*)d_in[3];    // [640,512]
  const float* Wo = (const float*)d_in[4];    // [1024,640]
  float* out = (float*)d_out;                 // [8,256,64,1024]

  char* ws = (char*)d_ws;
  u16* enc_bf = (u16*)ws;                     // 2,097,152 B
  u16* pred_bf = (u16*)(ws + 2097152);        //   524,288 B
  u16* We_bf = (u16*)(ws + 2621440);          //   655,360 B
  u16* Wp_bf = (u16*)(ws + 3276800);          //   655,360 B
  u16* Wo_bf = (u16*)(ws + 3932160);          // 1,310,720 B -> ends 5,242,880
  float* ep = (float*)(ws + 5242880);         // 5,242,880 B  [2048][640]
  float* pp = (float*)(ws + 10485760);        // 1,310,720 B  [512][640] -> ends 11,796,480
  u16* Wo_pk = (u16*)(ws + 11796480);         // 1,310,720 B packed fragments -> ends 13,107,200

  cast5_k<<<2048, 256, 0, stream>>>((const float4*)enc, (const float4*)pred,
                                    (const float4*)We, (const float4*)Wp,
                                    (const float4*)Wo, (ushort4*)ws);

  proj_k<<<dim3(16, 5), 256, 0, stream>>>(enc_bf, We_bf, ep);  // [2048][640]
  proj_k<<<dim3(4, 5), 256, 0, stream>>>(pred_bf, Wp_bf, pp);  // [512][640]
  pack_k<<<320, 256, 0, stream>>>(Wo_bf, Wo_pk);

  fused6_k<<<1024, 512, 0, stream>>>(ep, pp, Wo_pk, out);
}